// Round 5
// baseline (532.428 us; speedup 1.0000x reference)
//
#include <hip/hip_runtime.h>
#include <math.h>

// Problem constants
#define B_    256
#define T_    2048
#define DIN   64
#define H_    32
#define C_    16

// Time-chunking: chunk length 128, burn-in 96.
// One batch per 64-lane wave (split-row layout) -> B*NCHUNK = 4096 blocks.
#define CHUNK 128
#define WARM  96
#define NCHUNK (T_ / CHUNK)   // 16

// Workspace: u only (64 MiB at offset 0). hdec aliases into out[:, 0:32).
// (Scan prefetch overreads <=3 rows = 384 B past u's end for the last batch;
//  ws_size >= 65 MiB per rounds 0-3, so this stays inside the workspace.)
#define OFF_U 0u

__device__ __forceinline__ float fast_tanh(float x) {
    float e2 = __expf(x + x);
    return 1.0f - 2.0f * __builtin_amdgcn_rcpf(e2 + 1.0f);
}

// ---------------------------------------------------------------------------
// k1: u[r,i] = sum_d x[r,d]*W_in[i,d] + b_in[i] + b_res_enc[i]
// 128-row x tile staged in LDS via coalesced float4 loads.  (unchanged)
// ---------------------------------------------------------------------------
__global__ __launch_bounds__(256) void inproj_kernel(
        const float* __restrict__ x, const float* __restrict__ W_in,
        const float* __restrict__ b_in, const float* __restrict__ b_res_enc,
        float* __restrict__ u) {
    __shared__ __align__(16) float4 lx[128 * 16];   // 32 KiB: [row][k4]

    int tid  = threadIdx.x;
    int w    = tid >> 6;
    int lane = tid & 63;
    int i    = lane & 31;
    int par  = lane >> 5;

    float Wr[DIN];
    {
        const float4* wi4 = reinterpret_cast<const float4*>(W_in + i * DIN);
#pragma unroll
        for (int q = 0; q < DIN / 4; ++q) {
            float4 v = wi4[q];
            Wr[4*q+0] = v.x; Wr[4*q+1] = v.y; Wr[4*q+2] = v.z; Wr[4*q+3] = v.w;
        }
    }
    float bi = b_in[i] + b_res_enc[i];

    long row_base = (long)blockIdx.x * 128;
    const float4* xg = reinterpret_cast<const float4*>(x) + row_base * 16;

#pragma unroll
    for (int k = 0; k < 8; ++k)
        lx[tid + 256 * k] = xg[tid + 256 * k];
    __syncthreads();

#pragma unroll
    for (int g = 0; g < 4; ++g) {
        int r0 = w * 32 + g * 8 + par;      // rows r0, r0+2, r0+4, r0+6
        float acc0 = 0.f, acc1 = 0.f, acc2 = 0.f, acc3 = 0.f;
#pragma unroll
        for (int k4 = 0; k4 < 16; ++k4) {
            float4 wv = { Wr[4*k4+0], Wr[4*k4+1], Wr[4*k4+2], Wr[4*k4+3] };
            float4 x0 = lx[(r0 + 0) * 16 + k4];
            float4 x1 = lx[(r0 + 2) * 16 + k4];
            float4 x2 = lx[(r0 + 4) * 16 + k4];
            float4 x3 = lx[(r0 + 6) * 16 + k4];
            acc0 += x0.x * wv.x + x0.y * wv.y + x0.z * wv.z + x0.w * wv.w;
            acc1 += x1.x * wv.x + x1.y * wv.y + x1.z * wv.z + x1.w * wv.w;
            acc2 += x2.x * wv.x + x2.y * wv.y + x2.z * wv.z + x2.w * wv.w;
            acc3 += x3.x * wv.x + x3.y * wv.y + x3.z * wv.z + x3.w * wv.w;
        }
        long rg = row_base + r0;
        u[(rg + 0) * H_ + i] = acc0 + bi;
        u[(rg + 2) * H_ + i] = acc1 + bi;
        u[(rg + 4) * H_ + i] = acc2 + bi;
        u[(rg + 6) * H_ + i] = acc3 + bi;
    }
}

// ---------------------------------------------------------------------------
// k2: fused enc-scan -> W_comb -> dec-scan, split-row + STAGGERED step.
// Iteration t computes BOTH a = henc_t (from henc_{t-1}) and d = hdec_{t-1}
// (from henc_{t-1}, hdec_{t-2}) -> ONE packed float2 LDS write + ONE barrier
// + ONE gather per step (round 4 had two full round-trips per step).
// Lane (p,i): half-rows W[i, p*16:p*16+16] of We/Wc/Wd (48 regs) + half
// states (32 regs); cross-half reduce via __shfl_xor(...,32).
// hdec is written to out[r, 0:32); outproj later stages then overwrites.
// ---------------------------------------------------------------------------
template<bool DEC, bool STORE>
__device__ __forceinline__ void esn_step(
        const float (&We)[16], const float (&Wc)[16], const float (&Wd)[16],
        float (&he)[16], float (&hdv)[16],
        float ucur, float bcd, int i, int p,
        float2* lad, float* sp) {
    float e0 = 0.f, e1 = 0.f, e2 = 0.f, e3 = 0.f;
#pragma unroll
    for (int k = 0; k < 16; k += 4) {
        e0 += We[k+0] * he[k+0];
        e1 += We[k+1] * he[k+1];
        e2 += We[k+2] * he[k+2];
        e3 += We[k+3] * he[k+3];
    }
    float ep = (e0 + e1) + (e2 + e3);
    float gp = 0.f;
    if (DEC) {
        float g0 = 0.f, g1 = 0.f, g2 = 0.f, g3 = 0.f;
#pragma unroll
        for (int k = 0; k < 16; k += 2) {
            g0 += Wc[k+0] * he[k+0];
            g1 += Wc[k+1] * he[k+1];
            g2 += Wd[k+0] * hdv[k+0];
            g3 += Wd[k+1] * hdv[k+1];
        }
        gp = (g0 + g1) + (g2 + g3);
    }
    // two independent cross-half reduces + tanhs (good ILP)
    float ef = ep + __shfl_xor(ep, 32) + ucur;
    float gf = gp + __shfl_xor(gp, 32) + bcd;
    float a = fast_tanh(ef);
    float d = DEC ? fast_tanh(gf) : 0.f;
    if (STORE && p == 0) *sp = d;            // fire-and-forget, 128B coalesced
    lad[i] = make_float2(a, d);              // both halves write same value
    __syncthreads();
    const float4* s4 = reinterpret_cast<const float4*>(lad + p * 16);
#pragma unroll
    for (int q = 0; q < 8; ++q) {            // broadcast reads, conflict-free
        float4 v = s4[q];
        he[2*q+0]  = v.x; hdv[2*q+0] = v.y;
        he[2*q+1]  = v.z; hdv[2*q+1] = v.w;
    }
}

__global__ __launch_bounds__(64, 4) void scan_kernel(
        const float* __restrict__ u,
        const float* __restrict__ W_res_enc,
        const float* __restrict__ W_res_dec, const float* __restrict__ b_res_dec,
        const float* __restrict__ W_code, const float* __restrict__ b_code,
        const float* __restrict__ W_co,   const float* __restrict__ b_co,
        float* __restrict__ hd /* = out, row stride DIN, hdec in cols 0..31 */) {
    int lane = threadIdx.x;
    int i = lane & 31;            // row index
    int p = lane >> 5;            // column half: [p*16, p*16+16)
    int b = blockIdx.x & (B_ - 1);
    int c = blockIdx.x >> 8;
    int t0 = c * CHUNK;
    int tstart = (c == 0) ? 0 : (t0 - WARM);
    int tend = t0 + CHUNK;

    // --- stage W_code (16x32 = 2 KiB) in LDS for the W_comb prologue ---
    __shared__ __align__(16) float wcode[C_ * H_];
    {
        const float4* src = reinterpret_cast<const float4*>(W_code);
        float4* dst = reinterpret_cast<float4*>(wcode);
        dst[lane]      = src[lane];        // 128 float4, 64 lanes x 2
        dst[lane + 64] = src[lane + 64];
    }

    // --- load weight half-rows (once; L2-resident) ---
    float We[16], Wd[16], Wco_r[C_];
    {
        const float4* we4 = reinterpret_cast<const float4*>(W_res_enc + i * H_ + p * 16);
        const float4* wd4 = reinterpret_cast<const float4*>(W_res_dec + i * H_ + p * 16);
        const float4* wc4 = reinterpret_cast<const float4*>(W_co + i * C_);
#pragma unroll
        for (int q = 0; q < 4; ++q) {
            float4 a = we4[q], d = wd4[q], w = wc4[q];
            We[4*q+0]=a.x; We[4*q+1]=a.y; We[4*q+2]=a.z; We[4*q+3]=a.w;
            Wd[4*q+0]=d.x; Wd[4*q+1]=d.y; Wd[4*q+2]=d.z; Wd[4*q+3]=d.w;
            Wco_r[4*q+0]=w.x; Wco_r[4*q+1]=w.y; Wco_r[4*q+2]=w.z; Wco_r[4*q+3]=w.w;
        }
    }
    __syncthreads();

    // --- W_comb half-row: Wc[k] = sum_c W_co[i,c] * W_code[c, p*16+k] ---
    float Wc[16];
#pragma unroll
    for (int k = 0; k < 16; ++k) {
        float s = 0.f;
#pragma unroll
        for (int cc = 0; cc < C_; ++cc)
            s += Wco_r[cc] * wcode[cc * H_ + p * 16 + k];
        Wc[k] = s;
    }
    float bcd;   // b_comb[i] + b_res_dec[i]
    {
        float s = b_co[i] + b_res_dec[i];
#pragma unroll
        for (int cc = 0; cc < C_; ++cc)
            s += Wco_r[cc] * b_code[cc];
        bcd = s;
    }

    // --- states (half each): he = henc_{t-1}, hdv = hdec_{t-2} ---
    float he[16], hdv[16];
#pragma unroll
    for (int k = 0; k < 16; ++k) { he[k] = 0.f; hdv[k] = 0.f; }

    __shared__ __align__(16) float2 lad[H_];

    const float* ub = u  + ((long)b * T_) * H_ + i;    // both halves same addr
    float*       hp = hd + ((long)b * T_) * DIN + i + (long)t0 * DIN;

    // 3-deep u prefetch (biases folded in by inproj); incrementing pointer.
    const float* up = ub + (long)tstart * H_;
    float ucur = up[0];
    float un1  = up[H_];
    float un2  = up[2 * H_];
    up += 3 * H_;

    // ---- peel t = tstart: enc only; writes (a, 0) so hdec starts at 0 ----
    esn_step<false, false>(We, Wc, Wd, he, hdv, ucur, bcd, i, p, lad, nullptr);
    ucur = un1; un1 = un2; un2 = *up; up += H_;

    // ---- burn-in: t in (tstart, t0], no store ----
    for (int t = tstart + 1; t <= t0; ++t) {
        esn_step<true, false>(We, Wc, Wd, he, hdv, ucur, bcd, i, p, lad, nullptr);
        ucur = un1; un1 = un2; un2 = *up; up += H_;
    }

    // ---- main: t in (t0, tend); stores hdec_{t-1} ----
    for (int t = t0 + 1; t < tend; ++t) {
        esn_step<true, true>(We, Wc, Wd, he, hdv, ucur, bcd, i, p, lad, hp);
        hp += DIN;
        ucur = un1; un1 = un2; un2 = *up; up += H_;
    }

    // ---- final peel: dec only -> hdec_{tend-1} ----
    {
        float g0 = 0.f, g1 = 0.f, g2 = 0.f, g3 = 0.f;
#pragma unroll
        for (int k = 0; k < 16; k += 2) {
            g0 += Wc[k+0] * he[k+0];
            g1 += Wc[k+1] * he[k+1];
            g2 += Wd[k+0] * hdv[k+0];
            g3 += Wd[k+1] * hdv[k+1];
        }
        float gp = (g0 + g1) + (g2 + g3);
        float d = fast_tanh(gp + __shfl_xor(gp, 32) + bcd);
        if (p == 0) *hp = d;
    }
}

// ---------------------------------------------------------------------------
// k3: out[r,o] = sum_j hd[r,j] * W_ro[o,j] + b_ro[o]   (memory-bound)
// hd lives in out[r, 0:32). Stage 128 rows into LDS, sync, overwrite.
// Blocks own disjoint rows; same-stream kernels serialize -> no race.
// ---------------------------------------------------------------------------
__global__ __launch_bounds__(256) void outproj_kernel(
        const float* __restrict__ W_ro, const float* __restrict__ b_ro,
        float* __restrict__ out) {
    __shared__ __align__(16) float4 lh[128 * 8];    // 16 KiB: [row][q]

    int tid  = threadIdx.x;
    int w    = tid >> 6;
    int o    = tid & 63;

    float Wo[H_];
    {
        const float4* wo4 = reinterpret_cast<const float4*>(W_ro + o * H_);
#pragma unroll
        for (int q = 0; q < H_ / 4; ++q) {
            float4 v = wo4[q];
            Wo[4*q+0] = v.x; Wo[4*q+1] = v.y; Wo[4*q+2] = v.z; Wo[4*q+3] = v.w;
        }
    }
    float bo = b_ro[o];

    long row_base = (long)blockIdx.x * 128;
    const float4* hg = reinterpret_cast<const float4*>(out);

#pragma unroll
    for (int k = 0; k < 4; ++k) {
        int idx = tid + 256 * k;                 // 0..1023
        int r = idx >> 3, q = idx & 7;
        lh[idx] = hg[(row_base + r) * 16 + q];   // first half of each out row
    }
    __syncthreads();

    float* ob = out + (row_base + (long)w * 32) * DIN + o;
#pragma unroll 4
    for (int r = 0; r < 32; ++r) {
        int rr = w * 32 + r;
        float s0 = bo, s1 = 0.f, s2 = 0.f, s3 = 0.f;
#pragma unroll
        for (int q = 0; q < 8; ++q) {
            float4 h4 = lh[rr * 8 + q];       // broadcast: all lanes same addr
            s0 += Wo[4*q+0] * h4.x;
            s1 += Wo[4*q+1] * h4.y;
            s2 += Wo[4*q+2] * h4.z;
            s3 += Wo[4*q+3] * h4.w;
        }
        __builtin_nontemporal_store((s0 + s1) + (s2 + s3), ob + (long)r * DIN);
    }
}

extern "C" void kernel_launch(void* const* d_in, const int* in_sizes, int n_in,
                              void* d_out, int out_size, void* d_ws, size_t ws_size,
                              hipStream_t stream) {
    const float* x         = (const float*)d_in[0];
    const float* W_in      = (const float*)d_in[1];
    const float* b_in      = (const float*)d_in[2];
    const float* W_res_enc = (const float*)d_in[3];
    const float* b_res_enc = (const float*)d_in[4];
    const float* W_code    = (const float*)d_in[5];
    const float* b_code    = (const float*)d_in[6];
    const float* W_co      = (const float*)d_in[7];
    const float* b_co      = (const float*)d_in[8];
    const float* W_res_dec = (const float*)d_in[9];
    const float* b_res_dec = (const float*)d_in[10];
    const float* W_ro      = (const float*)d_in[11];
    const float* b_ro      = (const float*)d_in[12];
    float* out = (float*)d_out;

    float* u = (float*)((char*)d_ws + OFF_U);

    inproj_kernel<<<(B_ * T_) / 128, 256, 0, stream>>>(x, W_in, b_in, b_res_enc, u);
    scan_kernel<<<B_ * NCHUNK, 64, 0, stream>>>(u, W_res_enc,
                                                W_res_dec, b_res_dec,
                                                W_code, b_code, W_co, b_co, out);
    outproj_kernel<<<(B_ * T_) / 128, 256, 0, stream>>>(W_ro, b_ro, out);
}

// Round 7
// 499.257 us; speedup vs baseline: 1.0664x; 1.0664x over previous
//
#include <hip/hip_runtime.h>
#include <math.h>

// Problem constants
#define B_    256
#define T_    2048
#define DIN   64
#define H_    32
#define C_    16

// Time-chunking: chunk length 128, burn-in 96.
// One batch per 64-lane wave (split-row layout) -> B*NCHUNK = 4096 blocks.
#define CHUNK 128
#define WARM  96
#define NCHUNK (T_ / CHUNK)   // 16

// Workspace: u only (64 MiB). hdec aliases into out[:, 0:32).
#define OFF_U 0u

__device__ __forceinline__ float fast_tanh(float x) {
    float e2 = __expf(x + x);
    return 1.0f - 2.0f * __builtin_amdgcn_rcpf(e2 + 1.0f);
}

// ---------------------------------------------------------------------------
// k1: u[r,i] = sum_d x[r,d]*W_in[i,d] + b_in[i] + b_res_enc[i]
// 128-row x tile staged in LDS via coalesced float4 loads.  (unchanged)
// ---------------------------------------------------------------------------
__global__ __launch_bounds__(256) void inproj_kernel(
        const float* __restrict__ x, const float* __restrict__ W_in,
        const float* __restrict__ b_in, const float* __restrict__ b_res_enc,
        float* __restrict__ u) {
    __shared__ __align__(16) float4 lx[128 * 16];   // 32 KiB: [row][k4]

    int tid  = threadIdx.x;
    int w    = tid >> 6;
    int lane = tid & 63;
    int i    = lane & 31;
    int par  = lane >> 5;

    float Wr[DIN];
    {
        const float4* wi4 = reinterpret_cast<const float4*>(W_in + i * DIN);
#pragma unroll
        for (int q = 0; q < DIN / 4; ++q) {
            float4 v = wi4[q];
            Wr[4*q+0] = v.x; Wr[4*q+1] = v.y; Wr[4*q+2] = v.z; Wr[4*q+3] = v.w;
        }
    }
    float bi = b_in[i] + b_res_enc[i];

    long row_base = (long)blockIdx.x * 128;
    const float4* xg = reinterpret_cast<const float4*>(x) + row_base * 16;

#pragma unroll
    for (int k = 0; k < 8; ++k)
        lx[tid + 256 * k] = xg[tid + 256 * k];
    __syncthreads();

#pragma unroll
    for (int g = 0; g < 4; ++g) {
        int r0 = w * 32 + g * 8 + par;      // rows r0, r0+2, r0+4, r0+6
        float acc0 = 0.f, acc1 = 0.f, acc2 = 0.f, acc3 = 0.f;
#pragma unroll
        for (int k4 = 0; k4 < 16; ++k4) {
            float4 wv = { Wr[4*k4+0], Wr[4*k4+1], Wr[4*k4+2], Wr[4*k4+3] };
            float4 x0 = lx[(r0 + 0) * 16 + k4];
            float4 x1 = lx[(r0 + 2) * 16 + k4];
            float4 x2 = lx[(r0 + 4) * 16 + k4];
            float4 x3 = lx[(r0 + 6) * 16 + k4];
            acc0 += x0.x * wv.x + x0.y * wv.y + x0.z * wv.z + x0.w * wv.w;
            acc1 += x1.x * wv.x + x1.y * wv.y + x1.z * wv.z + x1.w * wv.w;
            acc2 += x2.x * wv.x + x2.y * wv.y + x2.z * wv.z + x2.w * wv.w;
            acc3 += x3.x * wv.x + x3.y * wv.y + x3.z * wv.z + x3.w * wv.w;
        }
        long rg = row_base + r0;
        u[(rg + 0) * H_ + i] = acc0 + bi;
        u[(rg + 2) * H_ + i] = acc1 + bi;
        u[(rg + 4) * H_ + i] = acc2 + bi;
        u[(rg + 6) * H_ + i] = acc3 + bi;
    }
}

// ---------------------------------------------------------------------------
// k2: fused enc-scan -> W_comb -> dec-scan, split-row layout (round-4 step
// structure: two-phase round-trip pipelines best). ONE change vs round 4:
// __launch_bounds__(64, 1). Round-4's (64,4) made the allocator squeeze to
// 64 arch VGPRs (vs a ~92-float live set) by parking values in AGPR/scratch
// — ~2x issued insts/step (VALU-issue math: 183 vs ~90 insts/wave/step).
// Supply caps residency at 4 waves/SIMD anyway, so 64 regs bought nothing.
// (64,1) is the proven round-3 syntax that yields use-what-you-need
// allocation; ~112 VGPRs still permits 4 waves/EU (<=128).
// ---------------------------------------------------------------------------
__global__ __launch_bounds__(64, 1) void scan_kernel(
        const float* __restrict__ u,
        const float* __restrict__ W_res_enc,
        const float* __restrict__ W_res_dec, const float* __restrict__ b_res_dec,
        const float* __restrict__ W_code, const float* __restrict__ b_code,
        const float* __restrict__ W_co,   const float* __restrict__ b_co,
        float* __restrict__ hd /* = out, row stride DIN, hdec in cols 0..31 */) {
    int lane = threadIdx.x;
    int i = lane & 31;            // row index
    int p = lane >> 5;            // column half: [p*16, p*16+16)
    int b = blockIdx.x & (B_ - 1);
    int c = blockIdx.x >> 8;
    int t0 = c * CHUNK;
    int tstart = (c == 0) ? 0 : (t0 - WARM);
    int tend = t0 + CHUNK;

    // --- stage W_code (16x32 = 2 KiB) in LDS for the W_comb prologue ---
    __shared__ __align__(16) float wcode[C_ * H_];
    {
        const float4* src = reinterpret_cast<const float4*>(W_code);
        float4* dst = reinterpret_cast<float4*>(wcode);
        dst[lane]      = src[lane];        // 128 float4, 64 lanes x 2
        dst[lane + 64] = src[lane + 64];
    }

    // --- load weight half-rows (once; L2-resident) ---
    float We[16], Wd[16], Wco_r[C_];
    {
        const float4* we4 = reinterpret_cast<const float4*>(W_res_enc + i * H_ + p * 16);
        const float4* wd4 = reinterpret_cast<const float4*>(W_res_dec + i * H_ + p * 16);
        const float4* wc4 = reinterpret_cast<const float4*>(W_co + i * C_);
#pragma unroll
        for (int q = 0; q < 4; ++q) {
            float4 a = we4[q], d = wd4[q], w = wc4[q];
            We[4*q+0]=a.x; We[4*q+1]=a.y; We[4*q+2]=a.z; We[4*q+3]=a.w;
            Wd[4*q+0]=d.x; Wd[4*q+1]=d.y; Wd[4*q+2]=d.z; Wd[4*q+3]=d.w;
            Wco_r[4*q+0]=w.x; Wco_r[4*q+1]=w.y; Wco_r[4*q+2]=w.z; Wco_r[4*q+3]=w.w;
        }
    }
    __syncthreads();

    // --- W_comb half-row: Wc[k] = sum_c W_co[i,c] * W_code[c, p*16+k] ---
    float Wc[16];
#pragma unroll
    for (int k = 0; k < 16; ++k) {
        float s = 0.f;
#pragma unroll
        for (int cc = 0; cc < C_; ++cc)
            s += Wco_r[cc] * wcode[cc * H_ + p * 16 + k];
        Wc[k] = s;
    }
    float bcd;   // b_comb[i] + b_res_dec[i]
    {
        float s = b_co[i] + b_res_dec[i];
#pragma unroll
        for (int cc = 0; cc < C_; ++cc)
            s += Wco_r[cc] * b_code[cc];
        bcd = s;
    }

    // --- states (half each) ---
    float he[16], hdv[16];
#pragma unroll
    for (int k = 0; k < 16; ++k) { he[k] = 0.f; hdv[k] = 0.f; }

    __shared__ __align__(16) float lhe[H_];
    __shared__ __align__(16) float lhd[H_];

    const float* ub = u  + ((long)b * T_) * H_ + i;    // both halves same addr
    float*       hb = hd + ((long)b * T_) * DIN + i;   // out[r, i], i<32

    // 3-deep u prefetch (b_in + b_res_enc folded in by inproj)
    float ucur = ub[(long)tstart * H_];
    float un1  = ub[(long)(tstart + 1) * H_];
    float un2  = ub[(long)(tstart + 2) * H_];

    // ---- burn-in: no store ----
    for (int t = tstart; t < t0; ++t) {
        float e0 = 0.f, e1 = 0.f, e2 = 0.f, e3 = 0.f;
#pragma unroll
        for (int k = 0; k < 16; k += 4) {
            e0 += We[k+0] * he[k+0];
            e1 += We[k+1] * he[k+1];
            e2 += We[k+2] * he[k+2];
            e3 += We[k+3] * he[k+3];
        }
        float ep = (e0 + e1) + (e2 + e3);
        float a = fast_tanh(ep + __shfl_xor(ep, 32) + ucur);
        lhe[i] = a;                          // both halves write same value
        __syncthreads();
        {
            const float4* s4 = reinterpret_cast<const float4*>(&lhe[p * 16]);
#pragma unroll
            for (int q = 0; q < 4; ++q) {
                float4 v = s4[q];
                he[4*q+0]=v.x; he[4*q+1]=v.y; he[4*q+2]=v.z; he[4*q+3]=v.w;
            }
        }
        float g0 = 0.f, g1 = 0.f, d0 = 0.f, d1 = 0.f;
#pragma unroll
        for (int k = 0; k < 16; k += 2) {
            g0 += Wc[k+0] * he[k+0];
            g1 += Wc[k+1] * he[k+1];
            d0 += Wd[k+0] * hdv[k+0];
            d1 += Wd[k+1] * hdv[k+1];
        }
        float part = (g0 + g1) + (d0 + d1);
        float d = fast_tanh(part + __shfl_xor(part, 32) + bcd);
        ucur = un1; un1 = un2;
        un2 = ub[(long)(t + 3) * H_];        // t+3 <= t0+2 < tend, in range
        lhd[i] = d;
        __syncthreads();
        {
            const float4* s4 = reinterpret_cast<const float4*>(&lhd[p * 16]);
#pragma unroll
            for (int q = 0; q < 4; ++q) {
                float4 v = s4[q];
                hdv[4*q+0]=v.x; hdv[4*q+1]=v.y; hdv[4*q+2]=v.z; hdv[4*q+3]=v.w;
            }
        }
    }

    // ---- main: + fire-and-forget hdec store by half 0 ----
    for (int t = t0; t < tend; ++t) {
        float e0 = 0.f, e1 = 0.f, e2 = 0.f, e3 = 0.f;
#pragma unroll
        for (int k = 0; k < 16; k += 4) {
            e0 += We[k+0] * he[k+0];
            e1 += We[k+1] * he[k+1];
            e2 += We[k+2] * he[k+2];
            e3 += We[k+3] * he[k+3];
        }
        float ep = (e0 + e1) + (e2 + e3);
        float a = fast_tanh(ep + __shfl_xor(ep, 32) + ucur);
        lhe[i] = a;
        __syncthreads();
        {
            const float4* s4 = reinterpret_cast<const float4*>(&lhe[p * 16]);
#pragma unroll
            for (int q = 0; q < 4; ++q) {
                float4 v = s4[q];
                he[4*q+0]=v.x; he[4*q+1]=v.y; he[4*q+2]=v.z; he[4*q+3]=v.w;
            }
        }
        float g0 = 0.f, g1 = 0.f, d0 = 0.f, d1 = 0.f;
#pragma unroll
        for (int k = 0; k < 16; k += 2) {
            g0 += Wc[k+0] * he[k+0];
            g1 += Wc[k+1] * he[k+1];
            d0 += Wd[k+0] * hdv[k+0];
            d1 += Wd[k+1] * hdv[k+1];
        }
        float part = (g0 + g1) + (d0 + d1);
        float d = fast_tanh(part + __shfl_xor(part, 32) + bcd);
        int tn = t + 3; if (tn > tend - 1) tn = tend - 1;
        ucur = un1; un1 = un2;
        un2 = ub[(long)tn * H_];
        if (p == 0) hb[(long)t * DIN] = d;   // coalesced 128B by lanes 0-31
        lhd[i] = d;
        __syncthreads();
        {
            const float4* s4 = reinterpret_cast<const float4*>(&lhd[p * 16]);
#pragma unroll
            for (int q = 0; q < 4; ++q) {
                float4 v = s4[q];
                hdv[4*q+0]=v.x; hdv[4*q+1]=v.y; hdv[4*q+2]=v.z; hdv[4*q+3]=v.w;
            }
        }
    }
}

// ---------------------------------------------------------------------------
// k3: out[r,o] = sum_j hd[r,j] * W_ro[o,j] + b_ro[o]   (memory-bound)
// hd lives in out[r, 0:32). Stage 128 rows into LDS, sync, overwrite.
// Blocks own disjoint rows; same-stream kernels serialize -> no race.
// ---------------------------------------------------------------------------
__global__ __launch_bounds__(256) void outproj_kernel(
        const float* __restrict__ W_ro, const float* __restrict__ b_ro,
        float* __restrict__ out) {
    __shared__ __align__(16) float4 lh[128 * 8];    // 16 KiB: [row][q]

    int tid  = threadIdx.x;
    int w    = tid >> 6;
    int o    = tid & 63;

    float Wo[H_];
    {
        const float4* wo4 = reinterpret_cast<const float4*>(W_ro + o * H_);
#pragma unroll
        for (int q = 0; q < H_ / 4; ++q) {
            float4 v = wo4[q];
            Wo[4*q+0] = v.x; Wo[4*q+1] = v.y; Wo[4*q+2] = v.z; Wo[4*q+3] = v.w;
        }
    }
    float bo = b_ro[o];

    long row_base = (long)blockIdx.x * 128;
    const float4* hg = reinterpret_cast<const float4*>(out);

#pragma unroll
    for (int k = 0; k < 4; ++k) {
        int idx = tid + 256 * k;                 // 0..1023
        int r = idx >> 3, q = idx & 7;
        lh[idx] = hg[(row_base + r) * 16 + q];   // first half of each out row
    }
    __syncthreads();

    float* ob = out + (row_base + (long)w * 32) * DIN + o;
#pragma unroll 4
    for (int r = 0; r < 32; ++r) {
        int rr = w * 32 + r;
        float s0 = bo, s1 = 0.f, s2 = 0.f, s3 = 0.f;
#pragma unroll
        for (int q = 0; q < 8; ++q) {
            float4 h4 = lh[rr * 8 + q];       // broadcast: all lanes same addr
            s0 += Wo[4*q+0] * h4.x;
            s1 += Wo[4*q+1] * h4.y;
            s2 += Wo[4*q+2] * h4.z;
            s3 += Wo[4*q+3] * h4.w;
        }
        __builtin_nontemporal_store((s0 + s1) + (s2 + s3), ob + (long)r * DIN);
    }
}

extern "C" void kernel_launch(void* const* d_in, const int* in_sizes, int n_in,
                              void* d_out, int out_size, void* d_ws, size_t ws_size,
                              hipStream_t stream) {
    const float* x         = (const float*)d_in[0];
    const float* W_in      = (const float*)d_in[1];
    const float* b_in      = (const float*)d_in[2];
    const float* W_res_enc = (const float*)d_in[3];
    const float* b_res_enc = (const float*)d_in[4];
    const float* W_code    = (const float*)d_in[5];
    const float* b_code    = (const float*)d_in[6];
    const float* W_co      = (const float*)d_in[7];
    const float* b_co      = (const float*)d_in[8];
    const float* W_res_dec = (const float*)d_in[9];
    const float* b_res_dec = (const float*)d_in[10];
    const float* W_ro      = (const float*)d_in[11];
    const float* b_ro      = (const float*)d_in[12];
    float* out = (float*)d_out;

    float* u = (float*)((char*)d_ws + OFF_U);

    inproj_kernel<<<(B_ * T_) / 128, 256, 0, stream>>>(x, W_in, b_in, b_res_enc, u);
    scan_kernel<<<B_ * NCHUNK, 64, 0, stream>>>(u, W_res_enc,
                                                W_res_dec, b_res_dec,
                                                W_code, b_code, W_co, b_co, out);
    outproj_kernel<<<(B_ * T_) / 128, 256, 0, stream>>>(W_ro, b_ro, out);
}

// Round 8
// 488.978 us; speedup vs baseline: 1.0889x; 1.0210x over previous
//
#include <hip/hip_runtime.h>
#include <math.h>

// Problem constants
#define B_    256
#define T_    2048
#define DIN   64
#define H_    32
#define C_    16

// Time-chunking: chunk length 128, burn-in 96.
// One batch per 64-lane wave (split-row layout) -> B*NCHUNK = 4096 blocks.
#define CHUNK 128
#define WARM  96
#define NCHUNK (T_ / CHUNK)   // 16

// Workspace: u only (64 MiB). hdec aliases into out[:, 0:32).
// (u prefetch over-reads <=384 B past u's end; ws_size >= 65 MiB proven
//  in rounds 0-3, so this stays inside the workspace.)
#define OFF_U 0u

__device__ __forceinline__ float fast_tanh(float x) {
    float e2 = __expf(x + x);
    return 1.0f - 2.0f * __builtin_amdgcn_rcpf(e2 + 1.0f);
}

// Zero-cost intra-wave ordering fence. Each scan workgroup is ONE wave, so
// __syncthreads() is semantically unnecessary — but it forces the compiler
// to emit s_waitcnt vmcnt(0) lgkmcnt(0) + s_barrier, which (a) drains the
// fire-and-forget hdec global store onto the critical path and (b) kills
// the 3-deep u prefetch, EVERY step, TWICE. wave_barrier() keeps program
// order for the LDS write->read (compiler inserts the lgkmcnt wait it
// derives from aliasing) with no vmcnt drain and no barrier instruction.
#define WAVE_FENCE() __builtin_amdgcn_wave_barrier()

// ---------------------------------------------------------------------------
// k1: u[r,i] = sum_d x[r,d]*W_in[i,d] + b_in[i] + b_res_enc[i]
// 128-row x tile staged in LDS via coalesced float4 loads.  (unchanged)
// ---------------------------------------------------------------------------
__global__ __launch_bounds__(256) void inproj_kernel(
        const float* __restrict__ x, const float* __restrict__ W_in,
        const float* __restrict__ b_in, const float* __restrict__ b_res_enc,
        float* __restrict__ u) {
    __shared__ __align__(16) float4 lx[128 * 16];   // 32 KiB: [row][k4]

    int tid  = threadIdx.x;
    int w    = tid >> 6;
    int lane = tid & 63;
    int i    = lane & 31;
    int par  = lane >> 5;

    float Wr[DIN];
    {
        const float4* wi4 = reinterpret_cast<const float4*>(W_in + i * DIN);
#pragma unroll
        for (int q = 0; q < DIN / 4; ++q) {
            float4 v = wi4[q];
            Wr[4*q+0] = v.x; Wr[4*q+1] = v.y; Wr[4*q+2] = v.z; Wr[4*q+3] = v.w;
        }
    }
    float bi = b_in[i] + b_res_enc[i];

    long row_base = (long)blockIdx.x * 128;
    const float4* xg = reinterpret_cast<const float4*>(x) + row_base * 16;

#pragma unroll
    for (int k = 0; k < 8; ++k)
        lx[tid + 256 * k] = xg[tid + 256 * k];
    __syncthreads();

#pragma unroll
    for (int g = 0; g < 4; ++g) {
        int r0 = w * 32 + g * 8 + par;      // rows r0, r0+2, r0+4, r0+6
        float acc0 = 0.f, acc1 = 0.f, acc2 = 0.f, acc3 = 0.f;
#pragma unroll
        for (int k4 = 0; k4 < 16; ++k4) {
            float4 wv = { Wr[4*k4+0], Wr[4*k4+1], Wr[4*k4+2], Wr[4*k4+3] };
            float4 x0 = lx[(r0 + 0) * 16 + k4];
            float4 x1 = lx[(r0 + 2) * 16 + k4];
            float4 x2 = lx[(r0 + 4) * 16 + k4];
            float4 x3 = lx[(r0 + 6) * 16 + k4];
            acc0 += x0.x * wv.x + x0.y * wv.y + x0.z * wv.z + x0.w * wv.w;
            acc1 += x1.x * wv.x + x1.y * wv.y + x1.z * wv.z + x1.w * wv.w;
            acc2 += x2.x * wv.x + x2.y * wv.y + x2.z * wv.z + x2.w * wv.w;
            acc3 += x3.x * wv.x + x3.y * wv.y + x3.z * wv.z + x3.w * wv.w;
        }
        long rg = row_base + r0;
        u[(rg + 0) * H_ + i] = acc0 + bi;
        u[(rg + 2) * H_ + i] = acc1 + bi;
        u[(rg + 4) * H_ + i] = acc2 + bi;
        u[(rg + 6) * H_ + i] = acc3 + bi;
    }
}

// ---------------------------------------------------------------------------
// k2: fused enc-scan -> W_comb -> dec-scan, split-row layout (round-4 step
// structure). ONE change vs round 7: __syncthreads() -> wave_barrier() in
// the step loops (see WAVE_FENCE comment). Single-wave workgroups need no
// HW barrier; this un-drains vmcnt so the u prefetch and hdec store overlap
// the compute instead of serializing it twice per step.
// ---------------------------------------------------------------------------
__global__ __launch_bounds__(64, 1) void scan_kernel(
        const float* __restrict__ u,
        const float* __restrict__ W_res_enc,
        const float* __restrict__ W_res_dec, const float* __restrict__ b_res_dec,
        const float* __restrict__ W_code, const float* __restrict__ b_code,
        const float* __restrict__ W_co,   const float* __restrict__ b_co,
        float* __restrict__ hd /* = out, row stride DIN, hdec in cols 0..31 */) {
    int lane = threadIdx.x;
    int i = lane & 31;            // row index
    int p = lane >> 5;            // column half: [p*16, p*16+16)
    int b = blockIdx.x & (B_ - 1);
    int c = blockIdx.x >> 8;
    int t0 = c * CHUNK;
    int tstart = (c == 0) ? 0 : (t0 - WARM);
    int tend = t0 + CHUNK;

    // --- stage W_code (16x32 = 2 KiB) in LDS for the W_comb prologue ---
    __shared__ __align__(16) float wcode[C_ * H_];
    {
        const float4* src = reinterpret_cast<const float4*>(W_code);
        float4* dst = reinterpret_cast<float4*>(wcode);
        dst[lane]      = src[lane];        // 128 float4, 64 lanes x 2
        dst[lane + 64] = src[lane + 64];
    }

    // --- load weight half-rows (once; L2-resident) ---
    float We[16], Wd[16], Wco_r[C_];
    {
        const float4* we4 = reinterpret_cast<const float4*>(W_res_enc + i * H_ + p * 16);
        const float4* wd4 = reinterpret_cast<const float4*>(W_res_dec + i * H_ + p * 16);
        const float4* wc4 = reinterpret_cast<const float4*>(W_co + i * C_);
#pragma unroll
        for (int q = 0; q < 4; ++q) {
            float4 a = we4[q], d = wd4[q], w = wc4[q];
            We[4*q+0]=a.x; We[4*q+1]=a.y; We[4*q+2]=a.z; We[4*q+3]=a.w;
            Wd[4*q+0]=d.x; Wd[4*q+1]=d.y; Wd[4*q+2]=d.z; Wd[4*q+3]=d.w;
            Wco_r[4*q+0]=w.x; Wco_r[4*q+1]=w.y; Wco_r[4*q+2]=w.z; Wco_r[4*q+3]=w.w;
        }
    }
    WAVE_FENCE();

    // --- W_comb half-row: Wc[k] = sum_c W_co[i,c] * W_code[c, p*16+k] ---
    float Wc[16];
#pragma unroll
    for (int k = 0; k < 16; ++k) {
        float s = 0.f;
#pragma unroll
        for (int cc = 0; cc < C_; ++cc)
            s += Wco_r[cc] * wcode[cc * H_ + p * 16 + k];
        Wc[k] = s;
    }
    float bcd;   // b_comb[i] + b_res_dec[i]
    {
        float s = b_co[i] + b_res_dec[i];
#pragma unroll
        for (int cc = 0; cc < C_; ++cc)
            s += Wco_r[cc] * b_code[cc];
        bcd = s;
    }

    // --- states (half each) ---
    float he[16], hdv[16];
#pragma unroll
    for (int k = 0; k < 16; ++k) { he[k] = 0.f; hdv[k] = 0.f; }

    __shared__ __align__(16) float lhe[H_];
    __shared__ __align__(16) float lhd[H_];

    const float* ub = u  + ((long)b * T_) * H_ + i;    // both halves same addr
    float*       hb = hd + ((long)b * T_) * DIN + i;   // out[r, i], i<32

    // 3-deep u prefetch (b_in + b_res_enc folded in by inproj)
    float ucur = ub[(long)tstart * H_];
    float un1  = ub[(long)(tstart + 1) * H_];
    float un2  = ub[(long)(tstart + 2) * H_];

    // ---- burn-in: no store ----
    for (int t = tstart; t < t0; ++t) {
        float e0 = 0.f, e1 = 0.f, e2 = 0.f, e3 = 0.f;
#pragma unroll
        for (int k = 0; k < 16; k += 4) {
            e0 += We[k+0] * he[k+0];
            e1 += We[k+1] * he[k+1];
            e2 += We[k+2] * he[k+2];
            e3 += We[k+3] * he[k+3];
        }
        float ep = (e0 + e1) + (e2 + e3);
        float a = fast_tanh(ep + __shfl_xor(ep, 32) + ucur);
        lhe[i] = a;                          // both halves write same value
        WAVE_FENCE();
        {
            const float4* s4 = reinterpret_cast<const float4*>(&lhe[p * 16]);
#pragma unroll
            for (int q = 0; q < 4; ++q) {
                float4 v = s4[q];
                he[4*q+0]=v.x; he[4*q+1]=v.y; he[4*q+2]=v.z; he[4*q+3]=v.w;
            }
        }
        float g0 = 0.f, g1 = 0.f, d0 = 0.f, d1 = 0.f;
#pragma unroll
        for (int k = 0; k < 16; k += 2) {
            g0 += Wc[k+0] * he[k+0];
            g1 += Wc[k+1] * he[k+1];
            d0 += Wd[k+0] * hdv[k+0];
            d1 += Wd[k+1] * hdv[k+1];
        }
        float part = (g0 + g1) + (d0 + d1);
        float d = fast_tanh(part + __shfl_xor(part, 32) + bcd);
        ucur = un1; un1 = un2;
        un2 = ub[(long)(t + 3) * H_];        // in-chunk range here
        lhd[i] = d;
        WAVE_FENCE();
        {
            const float4* s4 = reinterpret_cast<const float4*>(&lhd[p * 16]);
#pragma unroll
            for (int q = 0; q < 4; ++q) {
                float4 v = s4[q];
                hdv[4*q+0]=v.x; hdv[4*q+1]=v.y; hdv[4*q+2]=v.z; hdv[4*q+3]=v.w;
            }
        }
    }

    // ---- main: + truly fire-and-forget hdec store by half 0 ----
    for (int t = t0; t < tend; ++t) {
        float e0 = 0.f, e1 = 0.f, e2 = 0.f, e3 = 0.f;
#pragma unroll
        for (int k = 0; k < 16; k += 4) {
            e0 += We[k+0] * he[k+0];
            e1 += We[k+1] * he[k+1];
            e2 += We[k+2] * he[k+2];
            e3 += We[k+3] * he[k+3];
        }
        float ep = (e0 + e1) + (e2 + e3);
        float a = fast_tanh(ep + __shfl_xor(ep, 32) + ucur);
        lhe[i] = a;
        WAVE_FENCE();
        {
            const float4* s4 = reinterpret_cast<const float4*>(&lhe[p * 16]);
#pragma unroll
            for (int q = 0; q < 4; ++q) {
                float4 v = s4[q];
                he[4*q+0]=v.x; he[4*q+1]=v.y; he[4*q+2]=v.z; he[4*q+3]=v.w;
            }
        }
        float g0 = 0.f, g1 = 0.f, d0 = 0.f, d1 = 0.f;
#pragma unroll
        for (int k = 0; k < 16; k += 2) {
            g0 += Wc[k+0] * he[k+0];
            g1 += Wc[k+1] * he[k+1];
            d0 += Wd[k+0] * hdv[k+0];
            d1 += Wd[k+1] * hdv[k+1];
        }
        float part = (g0 + g1) + (d0 + d1);
        float d = fast_tanh(part + __shfl_xor(part, 32) + bcd);
        ucur = un1; un1 = un2;
        un2 = ub[(long)(t + 3) * H_];        // over-reads <=384 B past u: safe
        if (p == 0) hb[(long)t * DIN] = d;   // coalesced 128B by lanes 0-31
        lhd[i] = d;
        WAVE_FENCE();
        {
            const float4* s4 = reinterpret_cast<const float4*>(&lhd[p * 16]);
#pragma unroll
            for (int q = 0; q < 4; ++q) {
                float4 v = s4[q];
                hdv[4*q+0]=v.x; hdv[4*q+1]=v.y; hdv[4*q+2]=v.z; hdv[4*q+3]=v.w;
            }
        }
    }
}

// ---------------------------------------------------------------------------
// k3: out[r,o] = sum_j hd[r,j] * W_ro[o,j] + b_ro[o]   (memory-bound)
// hd lives in out[r, 0:32). Stage 128 rows into LDS, sync, overwrite.
// Blocks own disjoint rows; same-stream kernels serialize -> no race.
// (Multi-wave workgroup: keeps real __syncthreads.)
// ---------------------------------------------------------------------------
__global__ __launch_bounds__(256) void outproj_kernel(
        const float* __restrict__ W_ro, const float* __restrict__ b_ro,
        float* __restrict__ out) {
    __shared__ __align__(16) float4 lh[128 * 8];    // 16 KiB: [row][q]

    int tid  = threadIdx.x;
    int w    = tid >> 6;
    int o    = tid & 63;

    float Wo[H_];
    {
        const float4* wo4 = reinterpret_cast<const float4*>(W_ro + o * H_);
#pragma unroll
        for (int q = 0; q < H_ / 4; ++q) {
            float4 v = wo4[q];
            Wo[4*q+0] = v.x; Wo[4*q+1] = v.y; Wo[4*q+2] = v.z; Wo[4*q+3] = v.w;
        }
    }
    float bo = b_ro[o];

    long row_base = (long)blockIdx.x * 128;
    const float4* hg = reinterpret_cast<const float4*>(out);

#pragma unroll
    for (int k = 0; k < 4; ++k) {
        int idx = tid + 256 * k;                 // 0..1023
        int r = idx >> 3, q = idx & 7;
        lh[idx] = hg[(row_base + r) * 16 + q];   // first half of each out row
    }
    __syncthreads();

    float* ob = out + (row_base + (long)w * 32) * DIN + o;
#pragma unroll 4
    for (int r = 0; r < 32; ++r) {
        int rr = w * 32 + r;
        float s0 = bo, s1 = 0.f, s2 = 0.f, s3 = 0.f;
#pragma unroll
        for (int q = 0; q < 8; ++q) {
            float4 h4 = lh[rr * 8 + q];       // broadcast: all lanes same addr
            s0 += Wo[4*q+0] * h4.x;
            s1 += Wo[4*q+1] * h4.y;
            s2 += Wo[4*q+2] * h4.z;
            s3 += Wo[4*q+3] * h4.w;
        }
        __builtin_nontemporal_store((s0 + s1) + (s2 + s3), ob + (long)r * DIN);
    }
}

extern "C" void kernel_launch(void* const* d_in, const int* in_sizes, int n_in,
                              void* d_out, int out_size, void* d_ws, size_t ws_size,
                              hipStream_t stream) {
    const float* x         = (const float*)d_in[0];
    const float* W_in      = (const float*)d_in[1];
    const float* b_in      = (const float*)d_in[2];
    const float* W_res_enc = (const float*)d_in[3];
    const float* b_res_enc = (const float*)d_in[4];
    const float* W_code    = (const float*)d_in[5];
    const float* b_code    = (const float*)d_in[6];
    const float* W_co      = (const float*)d_in[7];
    const float* b_co      = (const float*)d_in[8];
    const float* W_res_dec = (const float*)d_in[9];
    const float* b_res_dec = (const float*)d_in[10];
    const float* W_ro      = (const float*)d_in[11];
    const float* b_ro      = (const float*)d_in[12];
    float* out = (float*)d_out;

    float* u = (float*)((char*)d_ws + OFF_U);

    inproj_kernel<<<(B_ * T_) / 128, 256, 0, stream>>>(x, W_in, b_in, b_res_enc, u);
    scan_kernel<<<B_ * NCHUNK, 64, 0, stream>>>(u, W_res_enc,
                                                W_res_dec, b_res_dec,
                                                W_code, b_code, W_co, b_co, out);
    outproj_kernel<<<(B_ * T_) / 128, 256, 0, stream>>>(W_ro, b_ro, out);
}